// Round 1
// baseline (4544.726 us; speedup 1.0000x reference)
//
#include <hip/hip_runtime.h>

#define DFEAT 128

// ---------------------------------------------------------------------------
// Per-destination degree count (float, for mean division)
// ---------------------------------------------------------------------------
__global__ __launch_bounds__(256) void count_kernel(const int* __restrict__ dst,
                                                    float* __restrict__ cnt, int E) {
    int e = blockIdx.x * 256 + threadIdx.x;
    if (e < E) unsafeAtomicAdd(&cnt[dst[e]], 1.0f);
}

// ---------------------------------------------------------------------------
// Edge-parallel scatter-add: agg[dst] += x_src[src]. 32 threads per edge,
// each handles 4 contiguous floats (float4 gather + 4 HW fp32 atomics).
// ---------------------------------------------------------------------------
__global__ __launch_bounds__(256) void scatter_kernel(const float* __restrict__ xsrc,
                                                      const int* __restrict__ src,
                                                      const int* __restrict__ dst,
                                                      float* __restrict__ agg, int E) {
    int tid = blockIdx.x * 256 + threadIdx.x;
    int e = tid >> 5;
    if (e >= E) return;
    int c = (tid & 31) << 2;
    int s = src[e];
    int d = dst[e];
    float4 v = *(const float4*)(xsrc + (size_t)s * DFEAT + c);
    float* p = agg + (size_t)d * DFEAT + c;
    unsafeAtomicAdd(p + 0, v.x);
    unsafeAtomicAdd(p + 1, v.y);
    unsafeAtomicAdd(p + 2, v.z);
    unsafeAtomicAdd(p + 3, v.w);
}

// ---------------------------------------------------------------------------
// Fused SAGE layer GEMM:
//   out[i] = prelu( (agg[i]/max(cnt[i],1)) @ Wl + bl + xdst[i] @ Wr , alpha )
// M rows, N=128, K=256 (mean part k<128 from agg*inv, root part from xdst).
// Block: 256 threads, BM=64 rows, full N=128. Each thread: 4 rows x 8 cols.
// Safe to run in-place (out == agg): each block writes only its own rows,
// after all its reads of those rows complete.
// ---------------------------------------------------------------------------
__global__ __launch_bounds__(256) void sage_gemm(const float* __restrict__ agg,
                                                 const float* __restrict__ cnt,
                                                 const float* __restrict__ xdst,
                                                 const float* __restrict__ Wlp,
                                                 const float* __restrict__ Wrp,
                                                 const float* __restrict__ bias,
                                                 const float* __restrict__ alpha,
                                                 float* __restrict__ out, int M) {
    __shared__ float in_t[64][36];      // 64 rows x 32 k, pad to 36 (aligned float4, 2-way max conflict)
    __shared__ float w_t[32][DFEAT];    // 32 k x 128 cols

    const int tid = threadIdx.x;
    const int row0 = blockIdx.x * 64;

    // compute tile: 4 rows x 8 cols per thread
    const int rb = (tid >> 4) << 2;     // 0,4,...,60
    const int cb = (tid & 15) << 3;     // 0,8,...,120

    // staging coords for in_t: 4 threads per row, 8 floats each
    const int sr = tid >> 2;            // 0..63
    const int sc = (tid & 3) << 3;      // 0,8,16,24
    const int grow = row0 + sr;
    const bool rvalid = grow < M;
    float inv = 0.0f;
    if (rvalid) inv = 1.0f / fmaxf(cnt[grow], 1.0f);

    // staging coords for w_t: 8 threads per k-row, 16 floats each
    const int wr = tid >> 3;            // 0..31
    const int wc = (tid & 7) << 4;      // 0,16,...,112

    float acc[4][8];
#pragma unroll
    for (int i = 0; i < 4; ++i)
#pragma unroll
        for (int j = 0; j < 8; ++j) acc[i][j] = 0.0f;

    for (int k0 = 0; k0 < 2 * DFEAT; k0 += 32) {
        // ---- global loads to registers ----
        float4 v0 = make_float4(0.f, 0.f, 0.f, 0.f), v1 = v0;
        float scale;
        const float* srcp;
        if (k0 < DFEAT) {
            srcp = agg + (size_t)grow * DFEAT + k0 + sc;
            scale = inv;
        } else {
            srcp = xdst + (size_t)grow * DFEAT + (k0 - DFEAT) + sc;
            scale = 1.0f;
        }
        if (rvalid) {
            v0 = *(const float4*)srcp;
            v1 = *(const float4*)(srcp + 4);
        }
        v0.x *= scale; v0.y *= scale; v0.z *= scale; v0.w *= scale;
        v1.x *= scale; v1.y *= scale; v1.z *= scale; v1.w *= scale;

        const float* wsrc = (k0 < DFEAT)
                                ? (Wlp + (size_t)(k0 + wr) * DFEAT + wc)
                                : (Wrp + (size_t)(k0 - DFEAT + wr) * DFEAT + wc);
        float4 w0 = *(const float4*)(wsrc + 0);
        float4 w1 = *(const float4*)(wsrc + 4);
        float4 w2 = *(const float4*)(wsrc + 8);
        float4 w3 = *(const float4*)(wsrc + 12);

        __syncthreads();   // previous iteration's LDS reads done
        *(float4*)&in_t[sr][sc + 0] = v0;
        *(float4*)&in_t[sr][sc + 4] = v1;
        *(float4*)&w_t[wr][wc + 0]  = w0;
        *(float4*)&w_t[wr][wc + 4]  = w1;
        *(float4*)&w_t[wr][wc + 8]  = w2;
        *(float4*)&w_t[wr][wc + 12] = w3;
        __syncthreads();   // stores visible

        // ---- compute ----
#pragma unroll
        for (int kk = 0; kk < 32; ++kk) {
            float a[4];
            a[0] = in_t[rb + 0][kk];
            a[1] = in_t[rb + 1][kk];
            a[2] = in_t[rb + 2][kk];
            a[3] = in_t[rb + 3][kk];
            float4 b0 = *(const float4*)&w_t[kk][cb + 0];
            float4 b1 = *(const float4*)&w_t[kk][cb + 4];
            float b[8] = {b0.x, b0.y, b0.z, b0.w, b1.x, b1.y, b1.z, b1.w};
#pragma unroll
            for (int i = 0; i < 4; ++i)
#pragma unroll
                for (int j = 0; j < 8; ++j) acc[i][j] += a[i] * b[j];
        }
    }

    // ---- epilogue: bias + PReLU, vectorized store ----
    float4 bb0 = *(const float4*)(bias + cb);
    float4 bb1 = *(const float4*)(bias + cb + 4);
    float4 aa0 = *(const float4*)(alpha + cb);
    float4 aa1 = *(const float4*)(alpha + cb + 4);
    float bv[8] = {bb0.x, bb0.y, bb0.z, bb0.w, bb1.x, bb1.y, bb1.z, bb1.w};
    float av[8] = {aa0.x, aa0.y, aa0.z, aa0.w, aa1.x, aa1.y, aa1.z, aa1.w};

#pragma unroll
    for (int i = 0; i < 4; ++i) {
        int r = row0 + rb + i;
        if (r < M) {
            float o[8];
#pragma unroll
            for (int j = 0; j < 8; ++j) {
                float x = acc[i][j] + bv[j];
                o[j] = (x >= 0.0f) ? x : av[j] * x;
            }
            *(float4*)(out + (size_t)r * DFEAT + cb + 0) = make_float4(o[0], o[1], o[2], o[3]);
            *(float4*)(out + (size_t)r * DFEAT + cb + 4) = make_float4(o[4], o[5], o[6], o[7]);
        }
    }
}

// ---------------------------------------------------------------------------
// Launcher.
// Inputs: 0 x_domain [N_DOM,128] f32, 1 x_ip [N_IP,128] f32,
//         2 ei_d2i [2,E] i32 (row0 src, row1 dst), 3 ei_i2d [2,E] i32,
//         4 Wl [2,2,128,128], 5 bl [2,2,128], 6 Wr [2,2,128,128], 7 alpha [2,128]
// Output: xd after 2 layers [N_DOM,128] f32.
// Layer-1 new_i is dead (output depends only on layer-1 new_d) -> skipped.
// d_out doubles as the layer-1 aggregation buffer (exactly N_DOM*128 floats).
// ---------------------------------------------------------------------------
extern "C" void kernel_launch(void* const* d_in, const int* in_sizes, int n_in,
                              void* d_out, int out_size, void* d_ws, size_t ws_size,
                              hipStream_t stream) {
    const float* x_dom  = (const float*)d_in[0];
    const float* x_ip   = (const float*)d_in[1];
    const int*   ei_d2i = (const int*)d_in[2];
    const int*   ei_i2d = (const int*)d_in[3];
    const float* Wl     = (const float*)d_in[4];
    const float* bl     = (const float*)d_in[5];
    const float* Wr     = (const float*)d_in[6];
    const float* alpha  = (const float*)d_in[7];
    float* out = (float*)d_out;

    const int n_dom = in_sizes[0] / DFEAT;
    const int n_ip  = in_sizes[1] / DFEAT;
    const int E     = in_sizes[2] / 2;

    // workspace layout (all f32): aggA_ip | aggA_dom | cnt_ip | cnt_dom
    float* aggA_ip  = (float*)d_ws;
    float* aggA_dom = aggA_ip + (size_t)n_ip * DFEAT;
    float* cnt_ip   = aggA_dom + (size_t)n_dom * DFEAT;
    float* cnt_dom  = cnt_ip + n_ip;
    size_t ws_used  = ((size_t)(n_ip + n_dom) * DFEAT + (size_t)n_ip + n_dom) * sizeof(float);

    hipMemsetAsync(d_ws, 0, ws_used, stream);
    hipMemsetAsync(d_out, 0, (size_t)out_size * sizeof(float), stream);

    const int* src_d2i = ei_d2i;
    const int* dst_d2i = ei_d2i + E;
    const int* src_i2d = ei_i2d;
    const int* dst_i2d = ei_i2d + E;

    const int cnt_grid = (E + 255) / 256;
    count_kernel<<<cnt_grid, 256, 0, stream>>>(dst_d2i, cnt_ip, E);
    count_kernel<<<cnt_grid, 256, 0, stream>>>(dst_i2d, cnt_dom, E);

    const int sc_grid = (int)(((size_t)E * 32 + 255) / 256);
    const size_t WSTRIDE = (size_t)DFEAT * DFEAT;  // 16384 per (l,e)

    // ---- Layer 0, new_i (dst = ip, etype 0): idx (0*2+0)=0 ----
    scatter_kernel<<<sc_grid, 256, 0, stream>>>(x_dom, src_d2i, dst_d2i, aggA_ip, E);
    sage_gemm<<<(n_ip + 63) / 64, 256, 0, stream>>>(
        aggA_ip, cnt_ip, x_ip,
        Wl + 0 * WSTRIDE, Wr + 0 * WSTRIDE, bl + 0 * DFEAT, alpha + 0 * DFEAT,
        aggA_ip /*in-place -> xi1*/, n_ip);

    // ---- Layer 0, new_d (dst = domain, etype 1): idx (0*2+1)=1 ----
    scatter_kernel<<<sc_grid, 256, 0, stream>>>(x_ip, src_i2d, dst_i2d, aggA_dom, E);
    sage_gemm<<<(n_dom + 63) / 64, 256, 0, stream>>>(
        aggA_dom, cnt_dom, x_dom,
        Wl + 1 * WSTRIDE, Wr + 1 * WSTRIDE, bl + 1 * DFEAT, alpha + 0 * DFEAT,
        aggA_dom /*in-place -> xd1*/, n_dom);

    // ---- Layer 1, new_d (dst = domain, etype 1): idx (1*2+1)=3, alpha[1] ----
    // (layer-1 new_i is never used by the output -> skipped)
    scatter_kernel<<<sc_grid, 256, 0, stream>>>(aggA_ip /*xi1*/, src_i2d, dst_i2d, out, E);
    sage_gemm<<<(n_dom + 63) / 64, 256, 0, stream>>>(
        out, cnt_dom, aggA_dom /*xd1*/,
        Wl + 3 * WSTRIDE, Wr + 3 * WSTRIDE, bl + 3 * DFEAT, alpha + 1 * DFEAT,
        out /*in-place -> final xd*/, n_dom);
}

// Round 2
// 867.938 us; speedup vs baseline: 5.2362x; 5.2362x over previous
//
#include <hip/hip_runtime.h>

#define DFEAT 128

// ===========================================================================
// CSR build: histogram -> block-scan row allocation -> bucket fill.
// Row allocation order across blocks is arbitrary (disjoint ranges), which
// is fine: gather only needs rowstart[i] / deg[i], not sorted rows.
// ===========================================================================
__global__ __launch_bounds__(256) void hist_kernel(const int* __restrict__ dst,
                                                   int* __restrict__ deg, int E) {
    int e = blockIdx.x * 256 + threadIdx.x;
    if (e < E) atomicAdd(&deg[dst[e]], 1);
}

__global__ __launch_bounds__(256) void alloc_rows(const int* __restrict__ deg,
                                                  int* __restrict__ rowstart,
                                                  int* __restrict__ cursor,
                                                  int n, int* __restrict__ counter) {
    __shared__ int sdata[256];
    __shared__ int sbase;
    int i = blockIdx.x * 256 + threadIdx.x;
    int v = (i < n) ? deg[i] : 0;
    sdata[threadIdx.x] = v;
    __syncthreads();
    // Hillis-Steele inclusive scan over 256 elements
    for (int off = 1; off < 256; off <<= 1) {
        int t = (threadIdx.x >= off) ? sdata[threadIdx.x - off] : 0;
        __syncthreads();
        sdata[threadIdx.x] += t;
        __syncthreads();
    }
    if (threadIdx.x == 255) sbase = atomicAdd(counter, sdata[255]);
    __syncthreads();
    if (i < n) {
        int start = sbase + sdata[threadIdx.x] - v;  // exclusive prefix
        rowstart[i] = start;
        cursor[i]   = start;
    }
}

__global__ __launch_bounds__(256) void fill_kernel(const int* __restrict__ src,
                                                   const int* __restrict__ dst,
                                                   int* __restrict__ cursor,
                                                   int* __restrict__ col, int E) {
    int e = blockIdx.x * 256 + threadIdx.x;
    if (e < E) {
        int pos = atomicAdd(&cursor[dst[e]], 1);
        col[pos] = src[e];
    }
}

// ===========================================================================
// Gather-mean aggregation: one wave (64 lanes) per destination node, each
// lane owns 2 contiguous feature columns (float2). No atomics; mean written
// once per node (zeros for isolated nodes).
// ===========================================================================
__global__ __launch_bounds__(256) void gather_mean(const float* __restrict__ xsrc,
                                                   const int* __restrict__ col,
                                                   const int* __restrict__ rowstart,
                                                   const int* __restrict__ deg,
                                                   float* __restrict__ mean, int n) {
    int wave = (blockIdx.x * 256 + threadIdx.x) >> 6;
    int lane = threadIdx.x & 63;
    if (wave >= n) return;
    int rs = rowstart[wave];
    int dg = deg[wave];
    float2 acc = make_float2(0.0f, 0.0f);
    int c = lane << 1;
    for (int j = 0; j < dg; ++j) {
        int s = col[rs + j];
        float2 v = *(const float2*)(xsrc + (size_t)s * DFEAT + c);
        acc.x += v.x;
        acc.y += v.y;
    }
    float invd = (dg > 0) ? 1.0f / (float)dg : 0.0f;
    acc.x *= invd;
    acc.y *= invd;
    *(float2*)(mean + (size_t)wave * DFEAT + c) = acc;
}

// ===========================================================================
// Fused SAGE layer GEMM:
//   out[i] = prelu( mean[i] @ Wl + bl + xdst[i] @ Wr , alpha )
// M rows, N=128, K=256. Block: 256 threads, BM=64, full N=128;
// each thread computes 4 rows x 8 cols. Safe in-place (out == mean):
// all reads of a block's rows precede its epilogue writes.
// ===========================================================================
__global__ __launch_bounds__(256) void sage_gemm(const float* __restrict__ meanp,
                                                 const float* __restrict__ xdst,
                                                 const float* __restrict__ Wlp,
                                                 const float* __restrict__ Wrp,
                                                 const float* __restrict__ bias,
                                                 const float* __restrict__ alpha,
                                                 float* __restrict__ out, int M) {
    __shared__ float in_t[64][36];
    __shared__ float w_t[32][DFEAT];

    const int tid = threadIdx.x;
    const int row0 = blockIdx.x * 64;

    const int rb = (tid >> 4) << 2;
    const int cb = (tid & 15) << 3;

    const int sr = tid >> 2;
    const int sc = (tid & 3) << 3;
    const int grow = row0 + sr;
    const bool rvalid = grow < M;

    const int wr = tid >> 3;
    const int wc = (tid & 7) << 4;

    float acc[4][8];
#pragma unroll
    for (int i = 0; i < 4; ++i)
#pragma unroll
        for (int j = 0; j < 8; ++j) acc[i][j] = 0.0f;

    for (int k0 = 0; k0 < 2 * DFEAT; k0 += 32) {
        float4 v0 = make_float4(0.f, 0.f, 0.f, 0.f), v1 = v0;
        const float* srcp = (k0 < DFEAT)
                                ? (meanp + (size_t)grow * DFEAT + k0 + sc)
                                : (xdst + (size_t)grow * DFEAT + (k0 - DFEAT) + sc);
        if (rvalid) {
            v0 = *(const float4*)srcp;
            v1 = *(const float4*)(srcp + 4);
        }

        const float* wsrc = (k0 < DFEAT)
                                ? (Wlp + (size_t)(k0 + wr) * DFEAT + wc)
                                : (Wrp + (size_t)(k0 - DFEAT + wr) * DFEAT + wc);
        float4 w0 = *(const float4*)(wsrc + 0);
        float4 w1 = *(const float4*)(wsrc + 4);
        float4 w2 = *(const float4*)(wsrc + 8);
        float4 w3 = *(const float4*)(wsrc + 12);

        __syncthreads();
        *(float4*)&in_t[sr][sc + 0] = v0;
        *(float4*)&in_t[sr][sc + 4] = v1;
        *(float4*)&w_t[wr][wc + 0]  = w0;
        *(float4*)&w_t[wr][wc + 4]  = w1;
        *(float4*)&w_t[wr][wc + 8]  = w2;
        *(float4*)&w_t[wr][wc + 12] = w3;
        __syncthreads();

#pragma unroll
        for (int kk = 0; kk < 32; ++kk) {
            float a[4];
            a[0] = in_t[rb + 0][kk];
            a[1] = in_t[rb + 1][kk];
            a[2] = in_t[rb + 2][kk];
            a[3] = in_t[rb + 3][kk];
            float4 b0 = *(const float4*)&w_t[kk][cb + 0];
            float4 b1 = *(const float4*)&w_t[kk][cb + 4];
            float b[8] = {b0.x, b0.y, b0.z, b0.w, b1.x, b1.y, b1.z, b1.w};
#pragma unroll
            for (int i = 0; i < 4; ++i)
#pragma unroll
                for (int j = 0; j < 8; ++j) acc[i][j] += a[i] * b[j];
        }
    }

    float4 bb0 = *(const float4*)(bias + cb);
    float4 bb1 = *(const float4*)(bias + cb + 4);
    float4 aa0 = *(const float4*)(alpha + cb);
    float4 aa1 = *(const float4*)(alpha + cb + 4);
    float bv[8] = {bb0.x, bb0.y, bb0.z, bb0.w, bb1.x, bb1.y, bb1.z, bb1.w};
    float av[8] = {aa0.x, aa0.y, aa0.z, aa0.w, aa1.x, aa1.y, aa1.z, aa1.w};

#pragma unroll
    for (int i = 0; i < 4; ++i) {
        int r = row0 + rb + i;
        if (r < M) {
            float o[8];
#pragma unroll
            for (int j = 0; j < 8; ++j) {
                float x = acc[i][j] + bv[j];
                o[j] = (x >= 0.0f) ? x : av[j] * x;
            }
            *(float4*)(out + (size_t)r * DFEAT + cb + 0) = make_float4(o[0], o[1], o[2], o[3]);
            *(float4*)(out + (size_t)r * DFEAT + cb + 4) = make_float4(o[4], o[5], o[6], o[7]);
        }
    }
}

// ===========================================================================
// Launcher. Layer-1 new_i is dead (output = xd only) -> 3 SAGE steps.
// i2d CSR reused for layer 0 and layer 1. d_out doubles as the layer-1
// mean buffer (exactly N_DOM*128 floats).
// ===========================================================================
extern "C" void kernel_launch(void* const* d_in, const int* in_sizes, int n_in,
                              void* d_out, int out_size, void* d_ws, size_t ws_size,
                              hipStream_t stream) {
    const float* x_dom  = (const float*)d_in[0];
    const float* x_ip   = (const float*)d_in[1];
    const int*   ei_d2i = (const int*)d_in[2];
    const int*   ei_i2d = (const int*)d_in[3];
    const float* Wl     = (const float*)d_in[4];
    const float* bl     = (const float*)d_in[5];
    const float* Wr     = (const float*)d_in[6];
    const float* alpha  = (const float*)d_in[7];
    float* out = (float*)d_out;

    const int n_dom = in_sizes[0] / DFEAT;
    const int n_ip  = in_sizes[1] / DFEAT;
    const int E     = in_sizes[2] / 2;

    // workspace layout (bytes):
    //   meanA_ip  [n_ip *128] f32   (also xi1 after in-place gemm)
    //   meanA_dom [n_dom*128] f32   (also xd1)
    //   col_d2i   [E] i32
    //   col_i2d   [E] i32
    //   rs_ip[n_ip] deg_ip[n_ip] rs_dom[n_dom] deg_dom[n_dom]
    //   cursor[max(n_ip,n_dom)]  counters[2]
    float* meanA_ip  = (float*)d_ws;
    float* meanA_dom = meanA_ip + (size_t)n_ip * DFEAT;
    int*   col_d2i   = (int*)(meanA_dom + (size_t)n_dom * DFEAT);
    int*   col_i2d   = col_d2i + E;
    int*   rs_ip     = col_i2d + E;
    int*   deg_ip    = rs_ip + n_ip;
    int*   rs_dom    = deg_ip + n_ip;
    int*   deg_dom   = rs_dom + n_dom;
    int*   cursor    = deg_dom + n_dom;
    int    ncur      = (n_ip > n_dom) ? n_ip : n_dom;
    int*   counters  = cursor + ncur;

    const int* src_d2i = ei_d2i;
    const int* dst_d2i = ei_d2i + E;
    const int* src_i2d = ei_i2d;
    const int* dst_i2d = ei_i2d + E;

    // zero: deg arrays + counters (small)
    hipMemsetAsync(deg_ip, 0, sizeof(int) * (size_t)(n_ip), stream);
    hipMemsetAsync(deg_dom, 0, sizeof(int) * (size_t)(n_dom), stream);
    hipMemsetAsync(counters, 0, sizeof(int) * 2, stream);

    const int egrid = (E + 255) / 256;
    const int gip   = (n_ip + 255) / 256;
    const int gdom  = (n_dom + 255) / 256;

    // ---- build CSR for d2i (dst = ip) and i2d (dst = dom) ----
    hist_kernel<<<egrid, 256, 0, stream>>>(dst_d2i, deg_ip, E);
    alloc_rows<<<gip, 256, 0, stream>>>(deg_ip, rs_ip, cursor, n_ip, counters + 0);
    fill_kernel<<<egrid, 256, 0, stream>>>(src_d2i, dst_d2i, cursor, col_d2i, E);

    hist_kernel<<<egrid, 256, 0, stream>>>(dst_i2d, deg_dom, E);
    alloc_rows<<<gdom, 256, 0, stream>>>(deg_dom, rs_dom, cursor, n_dom, counters + 1);
    fill_kernel<<<egrid, 256, 0, stream>>>(src_i2d, dst_i2d, cursor, col_i2d, E);

    const int wgip  = (n_ip * 64 + 255) / 256;   // 4 nodes per 256-thread block
    const int wgdom = (n_dom * 64 + 255) / 256;
    const size_t WSTRIDE = (size_t)DFEAT * DFEAT;

    // ---- Layer 0, new_i (dst = ip, etype 0) ----
    gather_mean<<<wgip, 256, 0, stream>>>(x_dom, col_d2i, rs_ip, deg_ip, meanA_ip, n_ip);
    sage_gemm<<<(n_ip + 63) / 64, 256, 0, stream>>>(
        meanA_ip, x_ip,
        Wl + 0 * WSTRIDE, Wr + 0 * WSTRIDE, bl + 0 * DFEAT, alpha + 0 * DFEAT,
        meanA_ip /* -> xi1 */, n_ip);

    // ---- Layer 0, new_d (dst = dom, etype 1) ----
    gather_mean<<<wgdom, 256, 0, stream>>>(x_ip, col_i2d, rs_dom, deg_dom, meanA_dom, n_dom);
    sage_gemm<<<(n_dom + 63) / 64, 256, 0, stream>>>(
        meanA_dom, x_dom,
        Wl + 1 * WSTRIDE, Wr + 1 * WSTRIDE, bl + 1 * DFEAT, alpha + 0 * DFEAT,
        meanA_dom /* -> xd1 */, n_dom);

    // ---- Layer 1, new_d (dst = dom, etype 1); layer-1 new_i is dead ----
    gather_mean<<<wgdom, 256, 0, stream>>>(meanA_ip /*xi1*/, col_i2d, rs_dom, deg_dom, out, n_dom);
    sage_gemm<<<(n_dom + 63) / 64, 256, 0, stream>>>(
        out, meanA_dom /*xd1*/,
        Wl + 3 * WSTRIDE, Wr + 3 * WSTRIDE, bl + 3 * DFEAT, alpha + 1 * DFEAT,
        out /* -> final xd */, n_dom);
}

// Round 3
// 699.482 us; speedup vs baseline: 6.4973x; 1.2408x over previous
//
#include <hip/hip_runtime.h>

#define DFEAT 128

typedef __attribute__((ext_vector_type(8))) short short8v;   // 8 bf16 (4 VGPRs)
typedef __attribute__((ext_vector_type(4))) float float4v;
typedef __attribute__((ext_vector_type(8))) unsigned short ushort8v;

__device__ __forceinline__ float bf2f(unsigned int u16) {
    union { unsigned int i; float f; } c; c.i = u16 << 16; return c.f;
}
__device__ __forceinline__ unsigned short f2bf(float f) {
    union { float f; unsigned int i; } c; c.f = f;
    return (unsigned short)((c.i + 0x7FFFu + ((c.i >> 16) & 1u)) >> 16);
}

// ===========================================================================
// f32 -> bf16 feature conversion (8 elems / thread, 16B stores)
// ===========================================================================
__global__ __launch_bounds__(256) void convert_bf16(const float* __restrict__ in,
                                                    unsigned short* __restrict__ out, int n8) {
    int i = blockIdx.x * 256 + threadIdx.x;
    if (i >= n8) return;
    const float4* p = (const float4*)(in + (size_t)i * 8);
    float4 a = p[0], b = p[1];
    ushort8v o;
    o[0] = f2bf(a.x); o[1] = f2bf(a.y); o[2] = f2bf(a.z); o[3] = f2bf(a.w);
    o[4] = f2bf(b.x); o[5] = f2bf(b.y); o[6] = f2bf(b.z); o[7] = f2bf(b.w);
    *(ushort8v*)(out + (size_t)i * 8) = o;
}

// ===========================================================================
// Weight prep: build per-(mat,kstep) LDS-image tiles.
// Wt layout: [3 mats][8 ksteps][128 n][4 chunks][8 bf16], where the chunk
// slot c_swz holds data chunk c_dat = c_swz ^ ((n>>1)&3)  (XOR swizzle).
// Logical B[k][n]: k<128 -> Wl[le][k][n], k>=128 -> Wr[le][k-128][n].
// mats: 0 -> le=0 (L0,ip), 1 -> le=1 (L0,dom), 2 -> le=3 (L1,dom).
// ===========================================================================
__global__ __launch_bounds__(256) void prep_weights(const float* __restrict__ Wl,
                                                    const float* __restrict__ Wr,
                                                    unsigned short* __restrict__ Wt) {
    int id = blockIdx.x * 256 + threadIdx.x;   // one 16B chunk per thread
    if (id >= 3 * 4096) return;
    int cw  = id & 3;
    int n   = (id >> 2) & 127;
    int ks  = (id >> 9) & 7;
    int mat = id >> 12;
    const int le_tab[3] = {0, 1, 3};
    int le = le_tab[mat];
    int cd = cw ^ ((n >> 1) & 3);
    int kbase = ks * 32 + cd * 8;
    ushort8v o;
#pragma unroll
    for (int j = 0; j < 8; ++j) {
        int k = kbase + j;
        float v = (k < DFEAT) ? Wl[((size_t)le * DFEAT + k) * DFEAT + n]
                              : Wr[((size_t)le * DFEAT + (k - DFEAT)) * DFEAT + n];
        o[j] = f2bf(v);
    }
    *(ushort8v*)(Wt + (size_t)id * 8) = o;
}

// ===========================================================================
// CSR build: histogram -> block-scan row allocation -> bucket fill.
// ===========================================================================
__global__ __launch_bounds__(256) void hist_kernel(const int* __restrict__ dst,
                                                   int* __restrict__ deg, int E) {
    int e = blockIdx.x * 256 + threadIdx.x;
    if (e < E) atomicAdd(&deg[dst[e]], 1);
}

__global__ __launch_bounds__(256) void alloc_rows(const int* __restrict__ deg,
                                                  int* __restrict__ rowstart,
                                                  int* __restrict__ cursor,
                                                  int n, int* __restrict__ counter) {
    __shared__ int sdata[256];
    __shared__ int sbase;
    int i = blockIdx.x * 256 + threadIdx.x;
    int v = (i < n) ? deg[i] : 0;
    sdata[threadIdx.x] = v;
    __syncthreads();
    for (int off = 1; off < 256; off <<= 1) {
        int t = (threadIdx.x >= off) ? sdata[threadIdx.x - off] : 0;
        __syncthreads();
        sdata[threadIdx.x] += t;
        __syncthreads();
    }
    if (threadIdx.x == 255) sbase = atomicAdd(counter, sdata[255]);
    __syncthreads();
    if (i < n) {
        int start = sbase + sdata[threadIdx.x] - v;
        rowstart[i] = start;
        cursor[i]   = start;
    }
}

__global__ __launch_bounds__(256) void fill_kernel(const int* __restrict__ src,
                                                   const int* __restrict__ dst,
                                                   int* __restrict__ cursor,
                                                   int* __restrict__ col, int E) {
    int e = blockIdx.x * 256 + threadIdx.x;
    if (e < E) {
        int pos = atomicAdd(&cursor[dst[e]], 1);
        col[pos] = src[e];
    }
}

// ===========================================================================
// Gather-mean (bf16 in, bf16 out, f32 accum): one wave per dst node,
// lane owns 2 contiguous cols (4B load per neighbor row).
// ===========================================================================
__global__ __launch_bounds__(256) void gather_mean_bf16(const unsigned short* __restrict__ xsrc,
                                                        const int* __restrict__ col,
                                                        const int* __restrict__ rowstart,
                                                        const int* __restrict__ deg,
                                                        unsigned short* __restrict__ meanb, int n) {
    int wv = (blockIdx.x * 256 + threadIdx.x) >> 6;
    int lane = threadIdx.x & 63;
    if (wv >= n) return;
    int rs = rowstart[wv];
    int dg = deg[wv];
    float ax = 0.0f, ay = 0.0f;
    const unsigned short* base = xsrc + 2 * lane;
    for (int j = 0; j < dg; ++j) {
        int s = col[rs + j];
        unsigned int v = *(const unsigned int*)(base + (size_t)s * DFEAT);
        ax += bf2f(v & 0xffffu);
        ay += bf2f(v >> 16);
    }
    float invd = (dg > 0) ? 1.0f / (float)dg : 0.0f;
    unsigned int o = (unsigned int)f2bf(ax * invd) | ((unsigned int)f2bf(ay * invd) << 16);
    *(unsigned int*)(meanb + (size_t)wv * DFEAT + 2 * lane) = o;
}

// ===========================================================================
// MFMA SAGE GEMM: out[i] = prelu([mean|xdst] @ [Wl;Wr] + bl, alpha)
// M x 128, K=256. Block = 256 thr (4 waves), BM=128, BK=32, 8 K-steps,
// double-buffered LDS via global_load_lds(16B) with XOR chunk swizzle
// (slot c holds data chunk c ^ ((row>>1)&3); same XOR applied on read).
// Wave w computes rows [w*32, w*32+32) x all 128 cols: 2x8 16x16 frags.
// In-place safe (outb may alias meanb): block reads only its own rows
// (clamp stays in-tile), writes after all reads.
// ===========================================================================
__global__ __launch_bounds__(256) void sage_gemm_mfma(
    const unsigned short* meanb,           // [M][128] bf16, k 0..127 (may alias outb)
    const unsigned short* xdstb,           // [M][128] bf16, k 128..255
    const unsigned short* __restrict__ Wt, // [8][128][4][8] bf16 tile image (one mat)
    const float* __restrict__ bias,
    const float* __restrict__ alpha,
    unsigned short* outb, float* outf,
    int M, int write_f32) {
    __shared__ short A_s[2][4096];
    __shared__ short B_s[2][4096];

    const int tid  = threadIdx.x;
    const int lane = tid & 63;
    const int wave = tid >> 6;
    const int row0 = blockIdx.x * 128;

    float4v acc[2][8];
#pragma unroll
    for (int i = 0; i < 2; ++i)
#pragma unroll
        for (int j = 0; j < 8; ++j) acc[i][j] = (float4v)(0.0f);

    // A stage: tile = [128 rows][4 chunks x 8 bf16]; linear slot s=(issue*256+tid):
    //   r = s>>2, c_swz = s&3, data chunk = c_swz ^ ((r>>1)&3)
    auto stageA = [&](int ks, int b) {
        const int k0 = ks * 32;
        const unsigned short* base = (k0 < DFEAT) ? meanb : xdstb;
        const int koff = k0 & (DFEAT - 1);
#pragma unroll
        for (int i = 0; i < 2; ++i) {
            int s = i * 256 + tid;
            int r = s >> 2;
            int cd = (s & 3) ^ ((r >> 1) & 3);
            int gr = row0 + r;
            if (gr > M - 1) gr = M - 1;
            const unsigned short* g = base + (size_t)gr * DFEAT + koff + cd * 8;
            __builtin_amdgcn_global_load_lds(
                (const __attribute__((address_space(1))) void*)g,
                (__attribute__((address_space(3))) void*)&A_s[b][i * 2048 + wave * 512],
                16, 0, 0);
        }
    };
    // B stage: linear 8KB copy from the pre-swizzled tile image
    auto stageB = [&](int ks, int b) {
#pragma unroll
        for (int i = 0; i < 2; ++i) {
            int s = i * 256 + tid;
            const unsigned short* g = Wt + (size_t)ks * 4096 + (size_t)s * 8;
            __builtin_amdgcn_global_load_lds(
                (const __attribute__((address_space(1))) void*)g,
                (__attribute__((address_space(3))) void*)&B_s[b][i * 2048 + wave * 512],
                16, 0, 0);
        }
    };

    int buf = 0;
    stageA(0, 0);
    stageB(0, 0);
    __syncthreads();

#pragma unroll
    for (int ks = 0; ks < 8; ++ks) {
        if (ks < 7) { stageA(ks + 1, buf ^ 1); stageB(ks + 1, buf ^ 1); }

        short8v a[2], bb[8];
#pragma unroll
        for (int rf = 0; rf < 2; ++rf) {
            int r = wave * 32 + rf * 16 + (lane & 15);
            int cs = (lane >> 4) ^ ((r >> 1) & 3);
            a[rf] = *(const short8v*)&A_s[buf][r * 32 + cs * 8];
        }
#pragma unroll
        for (int nf = 0; nf < 8; ++nf) {
            int n = nf * 16 + (lane & 15);
            int cs = (lane >> 4) ^ ((n >> 1) & 3);
            bb[nf] = *(const short8v*)&B_s[buf][n * 32 + cs * 8];
        }
#pragma unroll
        for (int rf = 0; rf < 2; ++rf)
#pragma unroll
            for (int nf = 0; nf < 8; ++nf)
                acc[rf][nf] = __builtin_amdgcn_mfma_f32_16x16x32_bf16(a[rf], bb[nf], acc[rf][nf], 0, 0, 0);

        __syncthreads();
        buf ^= 1;
    }

    // Epilogue: C/D layout col = lane&15, row = (lane>>4)*4 + v  [m89-verified]
#pragma unroll
    for (int nf = 0; nf < 8; ++nf) {
        int colx = nf * 16 + (lane & 15);
        float bv = bias[colx];
        float av = alpha[colx];
#pragma unroll
        for (int rf = 0; rf < 2; ++rf) {
            int rbase = row0 + wave * 32 + rf * 16 + (lane >> 4) * 4;
#pragma unroll
            for (int v = 0; v < 4; ++v) {
                int gr = rbase + v;
                if (gr < M) {
                    float x = acc[rf][nf][v] + bv;
                    x = (x >= 0.0f) ? x : av * x;
                    if (write_f32) outf[(size_t)gr * DFEAT + colx] = x;
                    else           outb[(size_t)gr * DFEAT + colx] = f2bf(x);
                }
            }
        }
    }
}

// ===========================================================================
// Launcher. 3 live SAGE steps (layer-1 new_i dead). All intermediates bf16.
// ===========================================================================
extern "C" void kernel_launch(void* const* d_in, const int* in_sizes, int n_in,
                              void* d_out, int out_size, void* d_ws, size_t ws_size,
                              hipStream_t stream) {
    const float* x_dom  = (const float*)d_in[0];
    const float* x_ip   = (const float*)d_in[1];
    const int*   ei_d2i = (const int*)d_in[2];
    const int*   ei_i2d = (const int*)d_in[3];
    const float* Wl     = (const float*)d_in[4];
    const float* bl     = (const float*)d_in[5];
    const float* Wr     = (const float*)d_in[6];
    const float* alpha  = (const float*)d_in[7];
    float* out = (float*)d_out;

    const int n_dom = in_sizes[0] / DFEAT;
    const int n_ip  = in_sizes[1] / DFEAT;
    const int E     = in_sizes[2] / 2;

    // ws layout: xb_dom | xb_ip | meanb_ip | meanb_dom | Wt | col_d2i | col_i2d | ints
    unsigned short* xb_dom    = (unsigned short*)d_ws;
    unsigned short* xb_ip     = xb_dom + (size_t)n_dom * DFEAT;   // reused as meanL1b later
    unsigned short* meanb_ip  = xb_ip + (size_t)n_ip * DFEAT;     // -> xi1b (in-place)
    unsigned short* meanb_dom = meanb_ip + (size_t)n_ip * DFEAT;  // -> xd1b (in-place)
    unsigned short* Wt        = meanb_dom + (size_t)n_dom * DFEAT;
    int* col_d2i   = (int*)(Wt + 3 * 32768);
    int* col_i2d   = col_d2i + E;
    int* rs_ip     = col_i2d + E;
    int* deg_ip    = rs_ip + n_ip;
    int* rs_dom    = deg_ip + n_ip;
    int* deg_dom   = rs_dom + n_dom;
    int* cursor    = deg_dom + n_dom;
    int  ncur      = (n_ip > n_dom) ? n_ip : n_dom;
    int* counters  = cursor + ncur;

    const int* src_d2i = ei_d2i;
    const int* dst_d2i = ei_d2i + E;
    const int* src_i2d = ei_i2d;
    const int* dst_i2d = ei_i2d + E;

    hipMemsetAsync(deg_ip, 0, sizeof(int) * (size_t)n_ip, stream);
    hipMemsetAsync(deg_dom, 0, sizeof(int) * (size_t)n_dom, stream);
    hipMemsetAsync(counters, 0, sizeof(int) * 2, stream);

    const int egrid = (E + 255) / 256;
    const int gip   = (n_ip + 255) / 256;
    const int gdom  = (n_dom + 255) / 256;

    // feature conversion + weight prep
    convert_bf16<<<(n_dom * DFEAT / 8 + 255) / 256, 256, 0, stream>>>(x_dom, xb_dom, n_dom * DFEAT / 8);
    convert_bf16<<<(n_ip * DFEAT / 8 + 255) / 256, 256, 0, stream>>>(x_ip, xb_ip, n_ip * DFEAT / 8);
    prep_weights<<<48, 256, 0, stream>>>(Wl, Wr, Wt);

    // CSR build
    hist_kernel<<<egrid, 256, 0, stream>>>(dst_d2i, deg_ip, E);
    alloc_rows<<<gip, 256, 0, stream>>>(deg_ip, rs_ip, cursor, n_ip, counters + 0);
    fill_kernel<<<egrid, 256, 0, stream>>>(src_d2i, dst_d2i, cursor, col_d2i, E);

    hist_kernel<<<egrid, 256, 0, stream>>>(dst_i2d, deg_dom, E);
    alloc_rows<<<gdom, 256, 0, stream>>>(deg_dom, rs_dom, cursor, n_dom, counters + 1);
    fill_kernel<<<egrid, 256, 0, stream>>>(src_i2d, dst_i2d, cursor, col_i2d, E);

    const int wgip  = (int)(((size_t)n_ip * 64 + 255) / 256);
    const int wgdom = (int)(((size_t)n_dom * 64 + 255) / 256);
    const int ggip  = (n_ip + 127) / 128;
    const int ggdom = (n_dom + 127) / 128;

    // ---- Layer 0, new_i (dst=ip, le=0, alpha[0]) ----
    gather_mean_bf16<<<wgip, 256, 0, stream>>>(xb_dom, col_d2i, rs_ip, deg_ip, meanb_ip, n_ip);
    sage_gemm_mfma<<<ggip, 256, 0, stream>>>(
        meanb_ip, xb_ip, Wt + 0 * 32768, bl + 0 * DFEAT, alpha + 0 * DFEAT,
        meanb_ip /*xi1b in-place*/, nullptr, n_ip, 0);

    // ---- Layer 0, new_d (dst=dom, le=1, alpha[0]) ----
    gather_mean_bf16<<<wgdom, 256, 0, stream>>>(xb_ip, col_i2d, rs_dom, deg_dom, meanb_dom, n_dom);
    sage_gemm_mfma<<<ggdom, 256, 0, stream>>>(
        meanb_dom, xb_dom, Wt + 1 * 32768, bl + 1 * DFEAT, alpha + 0 * DFEAT,
        meanb_dom /*xd1b in-place*/, nullptr, n_dom, 0);

    // ---- Layer 1, new_d (dst=dom, le=3, alpha[1]); new_i dead ----
    // xb_ip is dead now -> reuse as meanL1b
    unsigned short* meanL1b = xb_ip;
    gather_mean_bf16<<<wgdom, 256, 0, stream>>>(meanb_ip /*xi1b*/, col_i2d, rs_dom, deg_dom, meanL1b, n_dom);
    sage_gemm_mfma<<<ggdom, 256, 0, stream>>>(
        meanL1b, meanb_dom /*xd1b*/, Wt + 2 * 32768, bl + 3 * DFEAT, alpha + 1 * DFEAT,
        nullptr, out, n_dom, 1);
}

// Round 4
// 537.903 us; speedup vs baseline: 8.4490x; 1.3004x over previous
//
#include <hip/hip_runtime.h>

#define DFEAT 128

typedef __attribute__((ext_vector_type(8))) short short8v;   // 8 bf16 (4 VGPRs)
typedef __attribute__((ext_vector_type(4))) float float4v;
typedef __attribute__((ext_vector_type(8))) unsigned short ushort8v;

__device__ __forceinline__ float bf2f(unsigned int u16) {
    union { unsigned int i; float f; } c; c.i = u16 << 16; return c.f;
}
__device__ __forceinline__ unsigned short f2bf(float f) {
    union { float f; unsigned int i; } c; c.f = f;
    return (unsigned short)((c.i + 0x7FFFu + ((c.i >> 16) & 1u)) >> 16);
}

// ===========================================================================
// f32 -> bf16 feature conversion (8 elems / thread, 16B stores)
// ===========================================================================
__global__ __launch_bounds__(256) void convert_bf16(const float* __restrict__ in,
                                                    unsigned short* __restrict__ out, int n8) {
    int i = blockIdx.x * 256 + threadIdx.x;
    if (i >= n8) return;
    const float4* p = (const float4*)(in + (size_t)i * 8);
    float4 a = p[0], b = p[1];
    ushort8v o;
    o[0] = f2bf(a.x); o[1] = f2bf(a.y); o[2] = f2bf(a.z); o[3] = f2bf(a.w);
    o[4] = f2bf(b.x); o[5] = f2bf(b.y); o[6] = f2bf(b.z); o[7] = f2bf(b.w);
    *(ushort8v*)(out + (size_t)i * 8) = o;
}

// ===========================================================================
// Weight prep: Wt layout [3 mats][8 ksteps][128 n][4 chunks][8 bf16]; slot
// c_swz holds data chunk c_swz ^ ((n>>1)&3). Logical B[k][n]: k<128 ->
// Wl[le][k][n], else Wr[le][k-128][n]. mats: le = {0, 1, 3}.
// ===========================================================================
__global__ __launch_bounds__(256) void prep_weights(const float* __restrict__ Wl,
                                                    const float* __restrict__ Wr,
                                                    unsigned short* __restrict__ Wt) {
    int id = blockIdx.x * 256 + threadIdx.x;   // one 16B chunk per thread
    if (id >= 3 * 4096) return;
    int cw  = id & 3;
    int n   = (id >> 2) & 127;
    int ks  = (id >> 9) & 7;
    int mat = id >> 12;
    const int le_tab[3] = {0, 1, 3};
    int le = le_tab[mat];
    int cd = cw ^ ((n >> 1) & 3);
    int kbase = ks * 32 + cd * 8;
    ushort8v o;
#pragma unroll
    for (int j = 0; j < 8; ++j) {
        int k = kbase + j;
        float v = (k < DFEAT) ? Wl[((size_t)le * DFEAT + k) * DFEAT + n]
                              : Wr[((size_t)le * DFEAT + (k - DFEAT)) * DFEAT + n];
        o[j] = f2bf(v);
    }
    *(ushort8v*)(Wt + (size_t)id * 8) = o;
}

// ===========================================================================
// CSR build: histogram -> block-scan row allocation -> bucket fill.
// ===========================================================================
__global__ __launch_bounds__(256) void hist_kernel(const int* __restrict__ dst,
                                                   int* __restrict__ deg, int E) {
    int e = blockIdx.x * 256 + threadIdx.x;
    if (e < E) atomicAdd(&deg[dst[e]], 1);
}

__global__ __launch_bounds__(256) void alloc_rows(const int* __restrict__ deg,
                                                  int* __restrict__ rowstart,
                                                  int* __restrict__ cursor,
                                                  int n, int* __restrict__ counter) {
    __shared__ int sdata[256];
    __shared__ int sbase;
    int i = blockIdx.x * 256 + threadIdx.x;
    int v = (i < n) ? deg[i] : 0;
    sdata[threadIdx.x] = v;
    __syncthreads();
    for (int off = 1; off < 256; off <<= 1) {
        int t = (threadIdx.x >= off) ? sdata[threadIdx.x - off] : 0;
        __syncthreads();
        sdata[threadIdx.x] += t;
        __syncthreads();
    }
    if (threadIdx.x == 255) sbase = atomicAdd(counter, sdata[255]);
    __syncthreads();
    if (i < n) {
        int start = sbase + sdata[threadIdx.x] - v;
        rowstart[i] = start;
        cursor[i]   = start;
    }
}

__global__ __launch_bounds__(256) void fill_kernel(const int* __restrict__ src,
                                                   const int* __restrict__ dst,
                                                   int* __restrict__ cursor,
                                                   int* __restrict__ col, int E) {
    int e = blockIdx.x * 256 + threadIdx.x;
    if (e < E) {
        int pos = atomicAdd(&cursor[dst[e]], 1);
        col[pos] = src[e];
    }
}

// ===========================================================================
// Gather-mean v2: one wave per dst node; 4x16-lane groups each read a FULL
// 256B neighbor row (16B/lane) -> 4 rows in flight per VMEM instruction.
// Cross-group reduce via shfl_xor(16/32). Col indices prefetched one
// iteration ahead to break the col->row dependence chain.
// ===========================================================================
__global__ __launch_bounds__(256) void gather_mean_v2(const unsigned short* __restrict__ xsrc,
                                                      const int* __restrict__ col,
                                                      const int* __restrict__ rowstart,
                                                      const int* __restrict__ deg,
                                                      unsigned short* __restrict__ meanb, int n) {
    int wv = (blockIdx.x * 256 + threadIdx.x) >> 6;
    int lane = threadIdx.x & 63;
    if (wv >= n) return;
    int rs = rowstart[wv];
    int dg = deg[wv];
    int g = lane >> 4;          // neighbor sub-slot 0..3
    int i = lane & 15;          // 8-col chunk within row

    float acc[8];
#pragma unroll
    for (int t = 0; t < 8; ++t) acc[t] = 0.0f;

    const unsigned short* base = xsrc + i * 8;
    int s_cur = (g < dg) ? col[rs + g] : -1;
    for (int j = 0; j < dg; j += 4) {
        int s = s_cur;
        int jn = j + 4 + g;
        s_cur = (jn < dg) ? col[rs + jn] : -1;   // prefetch next quad
        if (s >= 0) {
            ushort8v v = *(const ushort8v*)(base + (size_t)s * DFEAT);
#pragma unroll
            for (int t = 0; t < 8; ++t) acc[t] += bf2f(v[t]);
        }
    }
#pragma unroll
    for (int t = 0; t < 8; ++t) {
        acc[t] += __shfl_xor(acc[t], 16);
        acc[t] += __shfl_xor(acc[t], 32);
    }
    if (g == 0) {
        float invd = (dg > 0) ? 1.0f / (float)dg : 0.0f;
        ushort8v o;
#pragma unroll
        for (int t = 0; t < 8; ++t) o[t] = f2bf(acc[t] * invd);
        *(ushort8v*)(meanb + (size_t)wv * DFEAT + i * 8) = o;
    }
}

// ===========================================================================
// MFMA SAGE GEMM v2: out[i] = prelu([mean|xdst] @ [Wl;Wr] + bl, alpha)
// Full B (256x128 bf16 = 64KB) staged in LDS ONCE; A-fragments loaded
// straight from global to registers (lane l holds A[row=l&15][k=(l>>4)*8+j],
// 16B/lane). 512 thr = 8 waves x 16 rows; 64 MFMA/wave; one barrier total.
// In-place safe (outb may alias meanb): all A reads complete before writes.
// ===========================================================================
__global__ __launch_bounds__(512) void sage_gemm_v2(
    const unsigned short* meanb,           // [M][128] bf16, k 0..127 (may alias outb)
    const unsigned short* xdstb,           // [M][128] bf16, k 128..255
    const unsigned short* __restrict__ Wt, // [8][128][4][8] bf16 image (one mat)
    const float* __restrict__ bias,
    const float* __restrict__ alpha,
    unsigned short* outb, float* outf,
    int M, int write_f32) {
    __shared__ short B_s[32768];           // 64KB: full K=256 x N=128

    const int tid  = threadIdx.x;
    const int lane = tid & 63;
    const int wave = tid >> 6;
    const int row0 = blockIdx.x * 128;

    // ---- A prefetch: 8 independent 16B loads (k-steps 0..7) ----
    int gr = row0 + wave * 16 + (lane & 15);
    if (gr > M - 1) gr = M - 1;
    const int ko = (lane >> 4) * 8;
    const unsigned short* rowm = meanb + (size_t)gr * DFEAT + ko;
    const unsigned short* rowx = xdstb + (size_t)gr * DFEAT + ko;
    short8v a[8];
#pragma unroll
    for (int ks = 0; ks < 4; ++ks) a[ks] = *(const short8v*)(rowm + ks * 32);
#pragma unroll
    for (int ks = 0; ks < 4; ++ks) a[4 + ks] = *(const short8v*)(rowx + ks * 32);

    // ---- B stage: 64KB linear copy via global_load_lds(16B) ----
#pragma unroll
    for (int it = 0; it < 8; ++it) {
        const unsigned short* g = Wt + ((size_t)it * 512 + tid) * 8;
        __builtin_amdgcn_global_load_lds(
            (const __attribute__((address_space(1))) void*)g,
            (__attribute__((address_space(3))) void*)&B_s[it * 4096 + wave * 512],
            16, 0, 0);
    }
    __syncthreads();

    float4v acc[8];
#pragma unroll
    for (int j = 0; j < 8; ++j) acc[j] = (float4v)(0.0f);

#pragma unroll
    for (int ks = 0; ks < 8; ++ks) {
#pragma unroll
        for (int nf = 0; nf < 8; ++nf) {
            int nn = nf * 16 + (lane & 15);
            int cs = (lane >> 4) ^ ((nn >> 1) & 3);
            short8v bb = *(const short8v*)&B_s[ks * 4096 + nn * 32 + cs * 8];
            acc[nf] = __builtin_amdgcn_mfma_f32_16x16x32_bf16(a[ks], bb, acc[nf], 0, 0, 0);
        }
    }

    // ---- epilogue: C/D layout col = lane&15, row = (lane>>4)*4 + v ----
#pragma unroll
    for (int nf = 0; nf < 8; ++nf) {
        int colx = nf * 16 + (lane & 15);
        float bv = bias[colx];
        float av = alpha[colx];
        int rbase = row0 + wave * 16 + (lane >> 4) * 4;
#pragma unroll
        for (int v = 0; v < 4; ++v) {
            int r = rbase + v;
            if (r < M) {
                float x = acc[nf][v] + bv;
                x = (x >= 0.0f) ? x : av * x;
                if (write_f32) outf[(size_t)r * DFEAT + colx] = x;
                else           outb[(size_t)r * DFEAT + colx] = f2bf(x);
            }
        }
    }
}

// ===========================================================================
// Launcher. 3 live SAGE steps (layer-1 new_i dead). All intermediates bf16.
// ===========================================================================
extern "C" void kernel_launch(void* const* d_in, const int* in_sizes, int n_in,
                              void* d_out, int out_size, void* d_ws, size_t ws_size,
                              hipStream_t stream) {
    const float* x_dom  = (const float*)d_in[0];
    const float* x_ip   = (const float*)d_in[1];
    const int*   ei_d2i = (const int*)d_in[2];
    const int*   ei_i2d = (const int*)d_in[3];
    const float* Wl     = (const float*)d_in[4];
    const float* bl     = (const float*)d_in[5];
    const float* Wr     = (const float*)d_in[6];
    const float* alpha  = (const float*)d_in[7];
    float* out = (float*)d_out;

    const int n_dom = in_sizes[0] / DFEAT;
    const int n_ip  = in_sizes[1] / DFEAT;
    const int E     = in_sizes[2] / 2;

    // ws layout: xb_dom | xb_ip | meanb_ip | meanb_dom | Wt | col_d2i | col_i2d | ints
    unsigned short* xb_dom    = (unsigned short*)d_ws;
    unsigned short* xb_ip     = xb_dom + (size_t)n_dom * DFEAT;   // reused as meanL1b later
    unsigned short* meanb_ip  = xb_ip + (size_t)n_ip * DFEAT;     // -> xi1b (in-place)
    unsigned short* meanb_dom = meanb_ip + (size_t)n_ip * DFEAT;  // -> xd1b (in-place)
    unsigned short* Wt        = meanb_dom + (size_t)n_dom * DFEAT;
    int* col_d2i   = (int*)(Wt + 3 * 32768);
    int* col_i2d   = col_d2i + E;
    int* rs_ip     = col_i2d + E;
    int* deg_ip    = rs_ip + n_ip;
    int* rs_dom    = deg_ip + n_ip;
    int* deg_dom   = rs_dom + n_dom;
    int* cursor    = deg_dom + n_dom;
    int  ncur      = (n_ip > n_dom) ? n_ip : n_dom;
    int* counters  = cursor + ncur;

    const int* src_d2i = ei_d2i;
    const int* dst_d2i = ei_d2i + E;
    const int* src_i2d = ei_i2d;
    const int* dst_i2d = ei_i2d + E;

    // one memset covers rs/deg/cursor/counters (rs+cursor rewritten anyway)
    hipMemsetAsync(rs_ip, 0, sizeof(int) * ((size_t)2 * n_ip + 2 * n_dom + ncur + 2), stream);

    const int egrid = (E + 255) / 256;
    const int gip   = (n_ip + 255) / 256;
    const int gdom  = (n_dom + 255) / 256;

    // feature conversion + weight prep
    convert_bf16<<<(n_dom * DFEAT / 8 + 255) / 256, 256, 0, stream>>>(x_dom, xb_dom, n_dom * DFEAT / 8);
    convert_bf16<<<(n_ip * DFEAT / 8 + 255) / 256, 256, 0, stream>>>(x_ip, xb_ip, n_ip * DFEAT / 8);
    prep_weights<<<48, 256, 0, stream>>>(Wl, Wr, Wt);

    // CSR build
    hist_kernel<<<egrid, 256, 0, stream>>>(dst_d2i, deg_ip, E);
    alloc_rows<<<gip, 256, 0, stream>>>(deg_ip, rs_ip, cursor, n_ip, counters + 0);
    fill_kernel<<<egrid, 256, 0, stream>>>(src_d2i, dst_d2i, cursor, col_d2i, E);

    hist_kernel<<<egrid, 256, 0, stream>>>(dst_i2d, deg_dom, E);
    alloc_rows<<<gdom, 256, 0, stream>>>(deg_dom, rs_dom, cursor, n_dom, counters + 1);
    fill_kernel<<<egrid, 256, 0, stream>>>(src_i2d, dst_i2d, cursor, col_i2d, E);

    const int wgip  = (int)(((size_t)n_ip * 64 + 255) / 256);
    const int wgdom = (int)(((size_t)n_dom * 64 + 255) / 256);
    const int ggip  = (n_ip + 127) / 128;
    const int ggdom = (n_dom + 127) / 128;

    // ---- Layer 0, new_i (dst=ip, le=0, alpha[0]) ----
    gather_mean_v2<<<wgip, 256, 0, stream>>>(xb_dom, col_d2i, rs_ip, deg_ip, meanb_ip, n_ip);
    sage_gemm_v2<<<ggip, 512, 0, stream>>>(
        meanb_ip, xb_ip, Wt + 0 * 32768, bl + 0 * DFEAT, alpha + 0 * DFEAT,
        meanb_ip /*xi1b in-place*/, nullptr, n_ip, 0);

    // ---- Layer 0, new_d (dst=dom, le=1, alpha[0]) ----
    gather_mean_v2<<<wgdom, 256, 0, stream>>>(xb_ip, col_i2d, rs_dom, deg_dom, meanb_dom, n_dom);
    sage_gemm_v2<<<ggdom, 512, 0, stream>>>(
        meanb_dom, xb_dom, Wt + 1 * 32768, bl + 1 * DFEAT, alpha + 0 * DFEAT,
        meanb_dom /*xd1b in-place*/, nullptr, n_dom, 0);

    // ---- Layer 1, new_d (dst=dom, le=3, alpha[1]); new_i dead ----
    unsigned short* meanL1b = xb_ip;   // xb_ip dead after gather1+gemm0
    gather_mean_v2<<<wgdom, 256, 0, stream>>>(meanb_ip /*xi1b*/, col_i2d, rs_dom, deg_dom, meanL1b, n_dom);
    sage_gemm_v2<<<ggdom, 512, 0, stream>>>(
        meanL1b, meanb_dom /*xd1b*/, Wt + 2 * 32768, bl + 3 * DFEAT, alpha + 1 * DFEAT,
        nullptr, out, n_dom, 1);
}